// Round 9
// baseline (1134.289 us; speedup 1.0000x reference)
//
#include <hip/hip_runtime.h>
#include <hip/hip_bf16.h>

// ---------------------------------------------------------------------------
// GINEdge: 3-layer GIN (sum agg) + per-layer edge MLP scoring.
//   relu([h_s,h_d]@W1+b1)@W2 == relu(P1[s]+P2[d])@W2,
//   P1 = h@W1[:64] + b1, P2 = h@W1[64:]  (per-node projections).
// R9 changes vs R8:
//   - gemm64/proj: weight column held in VGPRs (fully unrolled k), sx read
//     as float4 broadcast -> removes the LDS-BW bottleneck (sW reads were
//     512x256B/block vs 128 B/clk/CU LDS ceiling). Bit-identical numerics.
// Walks (fused score+agg), CSR build, scatter: unchanged from R8.
// ---------------------------------------------------------------------------

#define BN_EPS 1e-5f

static __device__ __forceinline__ float bf2f_lo(unsigned u) {
  return __uint_as_float(u << 16);
}
static __device__ __forceinline__ float bf2f_hi(unsigned u) {
  return __uint_as_float(u & 0xffff0000u);
}

__global__ __launch_bounds__(256) void hist_kernel(const int* __restrict__ dst,
                                                   int* __restrict__ deg, int E) {
  int i = blockIdx.x * blockDim.x + threadIdx.x;
  int stride = gridDim.x * blockDim.x;
  for (; i < E; i += stride) atomicAdd(&deg[dst[i]], 1);
}

// scan step 1: per-block (1024 elems) exclusive scan + block sum
__global__ __launch_bounds__(256) void scan1_kernel(const int* __restrict__ deg,
                                                    int* __restrict__ rowstart,
                                                    int* __restrict__ partials, int N) {
  __shared__ int wsum[4];
  int tid = threadIdx.x;
  int lane = tid & 63, w = tid >> 6;
  int base = blockIdx.x * 1024 + tid * 4;
  int d0 = 0, d1 = 0, d2 = 0, d3 = 0;
  if (base + 3 < N) {
    int4 v = *reinterpret_cast<const int4*>(deg + base);
    d0 = v.x; d1 = v.y; d2 = v.z; d3 = v.w;
  } else {
    if (base + 0 < N) d0 = deg[base + 0];
    if (base + 1 < N) d1 = deg[base + 1];
    if (base + 2 < N) d2 = deg[base + 2];
  }
  int t0 = d0, t1 = t0 + d1, t2 = t1 + d2, t3 = t2 + d3;
  int tot = t3;
  int inc = tot;
#pragma unroll
  for (int off = 1; off < 64; off <<= 1) {
    int v = __shfl_up(inc, off);
    if (lane >= off) inc += v;
  }
  if (lane == 63) wsum[w] = inc;
  __syncthreads();
  int woff = 0;
  for (int k = 0; k < w; ++k) woff += wsum[k];
  int excl = woff + inc - tot;
  if (base + 0 < N) rowstart[base + 0] = excl;
  if (base + 1 < N) rowstart[base + 1] = excl + t0;
  if (base + 2 < N) rowstart[base + 2] = excl + t1;
  if (base + 3 < N) rowstart[base + 3] = excl + t2;
  if (tid == 255) partials[blockIdx.x] = excl + t3;
}

// scan step 2 (merged): every block wave-scans the <=64 partials; adds its
// offset; mirrors into cursor.  Requires NB <= 64 (N <= 65536).
__global__ __launch_bounds__(256) void scan3_kernel(const int* __restrict__ partials,
                                                    int* __restrict__ rowstart,
                                                    int* __restrict__ cursor,
                                                    int N, int NB, int E) {
  __shared__ int s_off;
  int tid = threadIdx.x;
  if (tid < 64) {
    int v = (tid < NB) ? partials[tid] : 0;
    int inc = v;
#pragma unroll
    for (int off = 1; off < 64; off <<= 1) {
      int t = __shfl_up(inc, off);
      if (tid >= off) inc += t;
    }
    if (tid == (int)blockIdx.x) s_off = inc - v;
  }
  __syncthreads();
  int off = s_off;
  int base = blockIdx.x * 1024 + tid * 4;
#pragma unroll
  for (int k = 0; k < 4; ++k) {
    int i = base + k;
    if (i < N) {
      int r = rowstart[i] + off;
      rowstart[i] = r;
      cursor[i] = r;
    }
  }
  if (blockIdx.x == 0 && tid == 0) rowstart[N] = E;
}

__global__ __launch_bounds__(256) void fill_kernel(const int* __restrict__ src,
                                                   const int* __restrict__ dst,
                                                   int* __restrict__ cursor,
                                                   int2* __restrict__ epack, int E) {
  int i = blockIdx.x * blockDim.x + threadIdx.x;
  int stride = gridDim.x * blockDim.x;
  for (; i < E; i += stride) {
    int p = atomicAdd(&cursor[dst[i]], 1);
    epack[p] = make_int2(src[i], i);  // (src, original edge id) one 8B store
  }
}

// out[n][f] = bias[f] + sum_k in[n][k]*W[k][f]; col stats optional; optional
// bf16 mirror into packed G (row stride 128 ushorts), base = G + 64.
// W column cached in VGPRs (k fully unrolled); sx read as float4 broadcast.
__global__ __launch_bounds__(256) void gemm64_kernel(
    const float* __restrict__ in, const float* __restrict__ W,
    const float* __restrict__ bias, const float* __restrict__ stats_in,
    const float* __restrict__ g_in, const float* __restrict__ b_in,
    float* __restrict__ out, float* __restrict__ stats_out,
    ushort* __restrict__ out_g, int N) {
  __shared__ float sx[32][64];
  __shared__ float red[2][4][64];
  int tid = threadIdx.x;
  int lane = tid & 63, w = tid >> 6;
  int n0 = blockIdx.x * 32;
  // W column into regs: wreg[k] = W[k][lane]  (coalesced per k, L2-hot)
  float wreg[64];
#pragma unroll
  for (int k = 0; k < 64; ++k) wreg[k] = W[k * 64 + lane];
  float sc = 1.f, sh = 0.f;
  if (stats_in) {
    float invN = 1.0f / (float)N;
    float m = stats_in[lane] * invN;
    float var = stats_in[64 + lane] * invN - m * m;
    sc = g_in[lane] * rsqrtf(var + BN_EPS);
    sh = b_in[lane] - m * sc;
  }
#pragma unroll
  for (int r = 0; r < 8; ++r) {
    int idx = r * 256 + tid;  // (idx&63)==lane since 256%64==0
    int n = n0 + (idx >> 6);
    float x = (n < N) ? in[(size_t)n * 64 + lane] : 0.f;
    if (stats_in) x = fmaxf(x * sc + sh, 0.f);
    sx[idx >> 6][lane] = x;
  }
  __syncthreads();
  float acc[8];
  float bz = bias ? bias[lane] : 0.f;
#pragma unroll
  for (int j = 0; j < 8; ++j) acc[j] = bz;
#pragma unroll
  for (int k4 = 0; k4 < 16; ++k4) {
#pragma unroll
    for (int j = 0; j < 8; ++j) {
      float4 x = *reinterpret_cast<const float4*>(&sx[w * 8 + j][k4 * 4]);
      acc[j] = fmaf(x.x, wreg[4 * k4 + 0], acc[j]);
      acc[j] = fmaf(x.y, wreg[4 * k4 + 1], acc[j]);
      acc[j] = fmaf(x.z, wreg[4 * k4 + 2], acc[j]);
      acc[j] = fmaf(x.w, wreg[4 * k4 + 3], acc[j]);
    }
  }
  float ps = 0.f, pq = 0.f;
#pragma unroll
  for (int j = 0; j < 8; ++j) {
    int n = n0 + w * 8 + j;
    if (n < N) {
      out[(size_t)n * 64 + lane] = acc[j];
      if (out_g) {
        __hip_bfloat16 b = __float2bfloat16(acc[j]);
        out_g[(size_t)n * 128 + lane] = *reinterpret_cast<ushort*>(&b);
      }
      ps += acc[j];
      pq += acc[j] * acc[j];
    }
  }
  if (stats_out) {
    red[0][w][lane] = ps;
    red[1][w][lane] = pq;
    __syncthreads();
    if (w == 0) {
      float s = red[0][0][lane] + red[0][1][lane] + red[0][2][lane] + red[0][3][lane];
      float q = red[1][0][lane] + red[1][1][lane] + red[1][2][lane] + red[1][3][lane];
      atomicAdd(&stats_out[lane], s);
      atomicAdd(&stats_out[64 + lane], q);
    }
  }
}

// P1 = T(c) @ W1[0:64] + b1 -> packed G (stride 128, offset 0);
// P2 = T(c) @ W1[64:128]    -> separate bf16 [N][64].
// T = identity or relu-affine (deferred bn_out via stats_in).
// Split-k (2x32) register-cached W to bound VGPR use.
__global__ __launch_bounds__(256) void proj_kernel(
    const float* __restrict__ c, const float* __restrict__ W1,
    const float* __restrict__ b1, const float* __restrict__ stats_in,
    const float* __restrict__ g_in, const float* __restrict__ b_in,
    ushort* __restrict__ G, ushort* __restrict__ P2, int N) {
  __shared__ float sx[32][64];
  int tid = threadIdx.x, lane = tid & 63, w = tid >> 6;
  int n0 = blockIdx.x * 32;
  float sc = 1.f, sh = 0.f;
  if (stats_in) {
    float invN = 1.0f / (float)N;
    float m = stats_in[lane] * invN;
    float var = stats_in[64 + lane] * invN - m * m;
    sc = g_in[lane] * rsqrtf(var + BN_EPS);
    sh = b_in[lane] - m * sc;
  }
#pragma unroll
  for (int r = 0; r < 8; ++r) {
    int idx = r * 256 + tid;
    int n = n0 + (idx >> 6);
    float x = (n < N) ? c[(size_t)n * 64 + lane] : 0.f;
    if (stats_in) x = fmaxf(x * sc + sh, 0.f);
    sx[idx >> 6][lane] = x;
  }
  __syncthreads();
  float a1[8], a2[8];
  float bz = b1[lane];
#pragma unroll
  for (int j = 0; j < 8; ++j) { a1[j] = bz; a2[j] = 0.f; }
  for (int kb = 0; kb < 2; ++kb) {  // runtime kb: limits live W regs to 64
    float wa[32], wb[32];
#pragma unroll
    for (int k = 0; k < 32; ++k) {
      wa[k] = W1[(kb * 32 + k) * 64 + lane];
      wb[k] = W1[4096 + (kb * 32 + k) * 64 + lane];
    }
#pragma unroll
    for (int k4 = 0; k4 < 8; ++k4) {
#pragma unroll
      for (int j = 0; j < 8; ++j) {
        float4 x = *reinterpret_cast<const float4*>(&sx[w * 8 + j][kb * 32 + k4 * 4]);
        a1[j] = fmaf(x.x, wa[4 * k4 + 0], a1[j]);
        a2[j] = fmaf(x.x, wb[4 * k4 + 0], a2[j]);
        a1[j] = fmaf(x.y, wa[4 * k4 + 1], a1[j]);
        a2[j] = fmaf(x.y, wb[4 * k4 + 1], a2[j]);
        a1[j] = fmaf(x.z, wa[4 * k4 + 2], a1[j]);
        a2[j] = fmaf(x.z, wb[4 * k4 + 2], a2[j]);
        a1[j] = fmaf(x.w, wa[4 * k4 + 3], a1[j]);
        a2[j] = fmaf(x.w, wb[4 * k4 + 3], a2[j]);
      }
    }
  }
#pragma unroll
  for (int j = 0; j < 8; ++j) {
    int n = n0 + w * 8 + j;
    if (n < N) {
      __hip_bfloat16 b1v = __float2bfloat16(a1[j]);
      __hip_bfloat16 b2v = __float2bfloat16(a2[j]);
      G[(size_t)n * 128 + lane] = *reinterpret_cast<ushort*>(&b1v);
      P2[(size_t)n * 64 + lane] = *reinterpret_cast<ushort*>(&b2v);
    }
  }
}

// c = relu(bn(in)); col stats of c; bf16 mirror into packed G (offset 64).
__global__ __launch_bounds__(256) void bnrelu_kernel(
    const float* __restrict__ in, const float* __restrict__ stats_in,
    const float* __restrict__ g_in, const float* __restrict__ b_in,
    float* __restrict__ out, float* __restrict__ stats_out,
    ushort* __restrict__ out_g, int N) {
  __shared__ float red[2][4][64];
  int tid = threadIdx.x;
  int lane = tid & 63, w = tid >> 6;
  float invN = 1.0f / (float)N;
  float m = stats_in[lane] * invN;
  float var = stats_in[64 + lane] * invN - m * m;
  float sc = g_in[lane] * rsqrtf(var + BN_EPS);
  float sh = b_in[lane] - m * sc;
  float ps = 0.f, pq = 0.f;
  int rows_per_grid = gridDim.x * (blockDim.x >> 6);
  for (int n = blockIdx.x * (blockDim.x >> 6) + w; n < N; n += rows_per_grid) {
    float x = fmaxf(in[(size_t)n * 64 + lane] * sc + sh, 0.f);
    out[(size_t)n * 64 + lane] = x;
    __hip_bfloat16 b = __float2bfloat16(x);
    out_g[(size_t)n * 128 + lane] = *reinterpret_cast<ushort*>(&b);
    ps += x;
    pq += x * x;
  }
  if (stats_out) {
    red[0][w][lane] = ps;
    red[1][w][lane] = pq;
    __syncthreads();
    if (w == 0) {
      float s = red[0][0][lane] + red[0][1][lane] + red[0][2][lane] + red[0][3][lane];
      float q = red[1][0][lane] + red[1][1][lane] + red[1][2][lane] + red[1][3][lane];
      atomicAdd(&stats_out[lane], s);
      atomicAdd(&stats_out[64 + lane], q);
    }
  }
}

// FUSED per-layer edge walk: wave per dst node v; 4 groups x 16 lanes.
// Each group processes one edge per iter, loading the packed 256B record
// G[s] = [P1 row | cb row]:
//   lanes g16<8 : score  sc[p] (+)= relu(P1[s]+P2[v]) @ W2 + b2
//   lanes g16>=8: agg    acc += T(cb[s])   (T = relu-affine if TR)
// Epilogue: zb[v] = T(c[v]) + cross-group-reduced acc.
template <int TR>
__global__ __launch_bounds__(256) void score_agg_kernel(
    const ushort* __restrict__ G, const ushort* __restrict__ P2,
    const float* __restrict__ c, const int* __restrict__ rowstart,
    const int2* __restrict__ epack, const float* __restrict__ W2,
    const float* __restrict__ b2, const float* __restrict__ stats_tr,
    const float* __restrict__ g_tr, const float* __restrict__ b_tr,
    float2* __restrict__ sc, float* __restrict__ zb, int N, int first) {
  int lane = threadIdx.x & 63;
  int v = blockIdx.x * 4 + (threadIdx.x >> 6);
  if (v >= N) return;
  int grp = lane >> 4;  // 0..3 : edge slot
  int g16 = lane & 15;  // role within group
  int sub = g16 & 7;
  // score constants (lanes g16<8 use them)
  float w[16];
  {
    const float4* wp = reinterpret_cast<const float4*>(W2 + sub * 16);
#pragma unroll
    for (int k = 0; k < 4; ++k) {
      float4 t = wp[k];
      w[4 * k + 0] = t.x; w[4 * k + 1] = t.y; w[4 * k + 2] = t.z; w[4 * k + 3] = t.w;
    }
  }
  float bb0 = b2[0], bb1 = b2[1];
  uint4 pb = *reinterpret_cast<const uint4*>(P2 + (size_t)v * 64 + sub * 8);
  unsigned bv[4] = {pb.x, pb.y, pb.z, pb.w};
  // agg affine constants (lanes g16>=8 use them; also epilogue)
  float scv[8], shv[8];
  if (TR) {
    float invN = 1.0f / (float)N;
#pragma unroll
    for (int k = 0; k < 8; ++k) {
      int f = sub * 8 + k;
      float m = stats_tr[f] * invN;
      float var = stats_tr[64 + f] * invN - m * m;
      scv[k] = g_tr[f] * rsqrtf(var + BN_EPS);
      shv[k] = b_tr[f] - m * scv[k];
    }
  }
  float acc[8];
#pragma unroll
  for (int k = 0; k < 8; ++k) acc[k] = 0.f;

  int p0 = rowstart[v], p1 = rowstart[v + 1];
  for (int p = p0 + grp; p < p1; p += 4) {
    int s = epack[p].x;
    uint4 row = *reinterpret_cast<const uint4*>(G + (size_t)s * 128 + g16 * 8);
    unsigned rv[4] = {row.x, row.y, row.z, row.w};
    float q0 = 0.f, q1 = 0.f;
    if (g16 < 8) {
#pragma unroll
      for (int k = 0; k < 4; ++k) {
        float v0 = fmaxf(bf2f_lo(rv[k]) + bf2f_lo(bv[k]), 0.f);
        float v1 = fmaxf(bf2f_hi(rv[k]) + bf2f_hi(bv[k]), 0.f);
        q0 = fmaf(v0, w[4 * k + 0], fmaf(v1, w[4 * k + 2], q0));
        q1 = fmaf(v0, w[4 * k + 1], fmaf(v1, w[4 * k + 3], q1));
      }
    } else {
#pragma unroll
      for (int k = 0; k < 4; ++k) {
        float x0 = bf2f_lo(rv[k]);
        float x1 = bf2f_hi(rv[k]);
        if (TR) {
          x0 = fmaxf(x0 * scv[2 * k] + shv[2 * k], 0.f);
          x1 = fmaxf(x1 * scv[2 * k + 1] + shv[2 * k + 1], 0.f);
        }
        acc[2 * k] += x0;
        acc[2 * k + 1] += x1;
      }
    }
    // reduce score over the group's 8 score lanes (masks stay in-half)
#pragma unroll
    for (int mm = 1; mm < 8; mm <<= 1) {
      q0 += __shfl_xor(q0, mm);
      q1 += __shfl_xor(q1, mm);
    }
    if (g16 == 0) {
      float o0 = q0 + bb0, o1 = q1 + bb1;
      if (!first) {
        float2 prev = sc[p];
        o0 += prev.x;
        o1 += prev.y;
      }
      sc[p] = make_float2(o0, o1);
    }
  }
  // cross-group reduction of agg partials (lanes same g16 across groups)
#pragma unroll
  for (int k = 0; k < 8; ++k) {
    acc[k] += __shfl_xor(acc[k], 16);
    acc[k] += __shfl_xor(acc[k], 32);
  }
  if (grp == 0 && g16 >= 8) {
    const float* cv = c + (size_t)v * 64 + sub * 8;
    float4 c0 = *reinterpret_cast<const float4*>(cv);
    float4 c1 = *reinterpret_cast<const float4*>(cv + 4);
    float cf[8] = {c0.x, c0.y, c0.z, c0.w, c1.x, c1.y, c1.z, c1.w};
    float ov[8];
#pragma unroll
    for (int k = 0; k < 8; ++k) {
      float x = cf[k];
      if (TR) x = fmaxf(x * scv[k] + shv[k], 0.f);
      ov[k] = acc[k] + x;
    }
    float* zp = zb + (size_t)v * 64 + sub * 8;
    *reinterpret_cast<float4*>(zp) = make_float4(ov[0], ov[1], ov[2], ov[3]);
    *reinterpret_cast<float4*>(zp + 4) = make_float4(ov[4], ov[5], ov[6], ov[7]);
  }
}

// score-only CSR walk (last edge rep): 8 lanes/edge, P1 read from packed G.
__global__ __launch_bounds__(256) void edge_score_csr_kernel(
    const ushort* __restrict__ G, const ushort* __restrict__ P2,
    const int* __restrict__ rowstart, const int2* __restrict__ epack,
    const float* __restrict__ W2, const float* __restrict__ b2,
    float2* __restrict__ sc, int N, int first) {
  int lane = threadIdx.x & 63;
  int v = blockIdx.x * 4 + (threadIdx.x >> 6);
  if (v >= N) return;
  int sub = lane & 7;
  int grp = lane >> 3;
  float w[16];
  const float4* wp = reinterpret_cast<const float4*>(W2 + sub * 16);
#pragma unroll
  for (int k = 0; k < 4; ++k) {
    float4 t = wp[k];
    w[4 * k + 0] = t.x; w[4 * k + 1] = t.y; w[4 * k + 2] = t.z; w[4 * k + 3] = t.w;
  }
  float bb0 = b2[0], bb1 = b2[1];
  uint4 pb = *reinterpret_cast<const uint4*>(P2 + (size_t)v * 64 + sub * 8);
  unsigned bv[4] = {pb.x, pb.y, pb.z, pb.w};
  int p0 = rowstart[v], p1 = rowstart[v + 1];
  for (int p = p0 + grp; p < p1; p += 8) {
    int s = epack[p].x;
    uint4 pa = *reinterpret_cast<const uint4*>(G + (size_t)s * 128 + sub * 8);
    unsigned av[4] = {pa.x, pa.y, pa.z, pa.w};
    float q0 = 0.f, q1 = 0.f;
#pragma unroll
    for (int k = 0; k < 4; ++k) {
      float v0 = fmaxf(bf2f_lo(av[k]) + bf2f_lo(bv[k]), 0.f);
      float v1 = fmaxf(bf2f_hi(av[k]) + bf2f_hi(bv[k]), 0.f);
      q0 = fmaf(v0, w[4 * k + 0], fmaf(v1, w[4 * k + 2], q0));
      q1 = fmaf(v0, w[4 * k + 1], fmaf(v1, w[4 * k + 3], q1));
    }
#pragma unroll
    for (int mm = 1; mm < 8; mm <<= 1) {
      q0 += __shfl_xor(q0, mm);
      q1 += __shfl_xor(q1, mm);
    }
    if (sub == 0) {
      float o0 = q0 + bb0, o1 = q1 + bb1;
      if (!first) {
        float2 prev = sc[p];
        o0 += prev.x;
        o1 += prev.y;
      }
      sc[p] = make_float2(o0, o1);
    }
  }
}

// final permute: CSR-ordered scores -> original edge order
__global__ __launch_bounds__(256) void scatter_kernel(const float2* __restrict__ sc,
                                                      const int2* __restrict__ epack,
                                                      float2* __restrict__ out, int E) {
  int i = blockIdx.x * blockDim.x + threadIdx.x;
  int stride = gridDim.x * blockDim.x;
  for (; i < E; i += stride) out[epack[i].y] = sc[i];
}

extern "C" void kernel_launch(void* const* d_in, const int* in_sizes, int n_in,
                              void* d_out, int out_size, void* d_ws, size_t ws_size,
                              hipStream_t stream) {
  const float* h          = (const float*)d_in[0];
  const int*   src        = (const int*)d_in[1];
  const int*   dst        = (const int*)d_in[2];
  const float* emb_W      = (const float*)d_in[3];
  const float* emb_b      = (const float*)d_in[4];
  const float* mlp_W1     = (const float*)d_in[5];
  const float* mlp_b1     = (const float*)d_in[6];
  const float* mlp_bn_g   = (const float*)d_in[7];
  const float* mlp_bn_b   = (const float*)d_in[8];
  const float* mlp_W2     = (const float*)d_in[9];
  const float* mlp_b2     = (const float*)d_in[10];
  const float* apply_bn_g = (const float*)d_in[11];
  const float* apply_bn_b = (const float*)d_in[12];
  const float* out_bn_g   = (const float*)d_in[13];
  const float* out_bn_b   = (const float*)d_in[14];
  const float* pred_W1    = (const float*)d_in[15];
  const float* pred_b1    = (const float*)d_in[16];
  const float* pred_W2    = (const float*)d_in[17];
  const float* pred_b2    = (const float*)d_in[18];

  const int N = in_sizes[0] / 64;
  const int E = in_sizes[1];
  const size_t NF = (size_t)N * 64;
  const int NB1 = (N + 1023) / 1024;  // scan3 requires NB1 <= 64 (N <= 65536)

  float* ws = (float*)d_ws;
  float* c   = ws;            // current node features (f32), pre-bn_out
  float* z1  = c + NF;
  float* zb  = z1 + NF;       // agg output; ALSO reused as z2 (disjoint lifetime)
  ushort* G  = (ushort*)(zb + NF);  // packed [N][128]: [0..63]=P1, [64..127]=cb
  ushort* P2 = G + (size_t)N * 128;
  int2*   epack = (int2*)(P2 + NF); // (src, orig edge id) per CSR slot
  float2* scbuf = (float2*)(epack + E);
  int* rowstart = (int*)(scbuf + E);          // N+1 (padded)
  int* cursor   = rowstart + (N + 64);
  int* partials = cursor + (N + 64);          // 64
  int* deg      = partials + 64;
  float* stats  = (float*)(deg + (N + 64));   // 9 slots x [sum(64), sumsq(64)]

  size_t need = (size_t)((char*)(stats + 9 * 128) - (char*)d_ws);
  if (need > ws_size) return;

  hipMemsetAsync(deg, 0, ((size_t)(N + 64) + 9 * 128) * sizeof(int), stream);

  const int gemmBlocks = (N + 31) / 32;
  const int nodeBlocks = (N + 3) / 4;

  // embedding: c = h @ emb_W + emb_b  (+ cb into packed G)
  gemm64_kernel<<<gemmBlocks, 256, 0, stream>>>(h, emb_W, emb_b, nullptr, nullptr,
                                                nullptr, c, nullptr, G + 64, N);
  // CSR build (by dst)
  hist_kernel<<<1024, 256, 0, stream>>>(dst, deg, E);
  scan1_kernel<<<NB1, 256, 0, stream>>>(deg, rowstart, partials, N);
  scan3_kernel<<<NB1, 256, 0, stream>>>(partials, rowstart, cursor, N, NB1, E);
  fill_kernel<<<1024, 256, 0, stream>>>(src, dst, cursor, epack, E);

  // rep 0: proj (identity) then fused score0 + agg(layer0)
  proj_kernel<<<gemmBlocks, 256, 0, stream>>>(c, pred_W1, pred_b1, nullptr, nullptr,
                                              nullptr, G, P2, N);
  score_agg_kernel<0><<<nodeBlocks, 256, 0, stream>>>(
      G, P2, c, rowstart, epack, pred_W2, pred_b2, nullptr, nullptr, nullptr,
      scbuf, zb, N, 1);

  for (int i = 0; i < 3; ++i) {
    float* st1 = stats + (size_t)(3 * i + 0) * 128;
    float* st2 = stats + (size_t)(3 * i + 1) * 128;
    float* st3 = stats + (size_t)(3 * i + 2) * 128;

    // z1 = zb @ W1 + b1  (+ stats st1)
    gemm64_kernel<<<gemmBlocks, 256, 0, stream>>>(zb, mlp_W1 + (size_t)i * 4096,
                                                  mlp_b1 + i * 64, nullptr, nullptr,
                                                  nullptr, z1, st1, nullptr, N);
    // z2(=zb) = relu(bn_mlp(z1)) @ W2 + b2  (+ stats st2)
    gemm64_kernel<<<gemmBlocks, 256, 0, stream>>>(z1, mlp_W2 + (size_t)i * 4096,
                                                  mlp_b2 + i * 64, st1,
                                                  mlp_bn_g + i * 64, mlp_bn_b + i * 64,
                                                  zb, st2, nullptr, N);
    // c = relu(bn_apply(z2))  (+ stats st3, cb into packed G); bn_out deferred
    bnrelu_kernel<<<784, 256, 0, stream>>>(zb, st2, apply_bn_g + i * 64,
                                           apply_bn_b + i * 64, c, st3, G + 64, N);
    // proj rep i+1 (applies deferred bn_out[i] via st3)
    proj_kernel<<<gemmBlocks, 256, 0, stream>>>(c, pred_W1 + (size_t)(i + 1) * 8192,
                                                pred_b1 + (i + 1) * 64, st3,
                                                out_bn_g + i * 64, out_bn_b + i * 64,
                                                G, P2, N);
    if (i < 2) {
      // fused: score rep i+1 + agg for layer i+1 (affine T via st3/out_bn)
      score_agg_kernel<1><<<nodeBlocks, 256, 0, stream>>>(
          G, P2, c, rowstart, epack, pred_W2 + (i + 1) * 128,
          pred_b2 + (i + 1) * 2, st3, out_bn_g + i * 64, out_bn_b + i * 64,
          scbuf, zb, N, 0);
    } else {
      // last rep: score only
      edge_score_csr_kernel<<<nodeBlocks, 256, 0, stream>>>(
          G, P2, rowstart, epack, pred_W2 + (i + 1) * 128,
          pred_b2 + (i + 1) * 2, scbuf, N, 0);
    }
  }

  // CSR order -> original edge order
  scatter_kernel<<<2048, 256, 0, stream>>>(scbuf, epack, (float2*)d_out, E);
}

// Round 10
// 843.177 us; speedup vs baseline: 1.3453x; 1.3453x over previous
//
#include <hip/hip_runtime.h>
#include <hip/hip_bf16.h>

// ---------------------------------------------------------------------------
// GINEdge: 3-layer GIN (sum agg) + per-layer edge MLP scoring.
//   relu([h_s,h_d]@W1+b1)@W2 == relu(P1[s]+P2[d])@W2,
//   P1 = h@W1[:64] + b1, P2 = h@W1[64:]  (per-node projections).
// R10 changes vs R8 (R9's register-W spilled -> reverted):
//   - gemm64/proj rebuilt as 4x4-microtile GEMM over a TRANSPOSED LDS
//     activation tile sxT[k][row] (stride 68): per k, 2-3 ds_read_b128 for
//     16-32 FMAs (was 9 LDS ops per 8 FMAs). Bit-identical k-order.
//   - last edge-score walk writes d_out[eord] directly (scatter pass gone).
// Walks (fused score+agg), CSR build, bnrelu: unchanged from R8.
// ---------------------------------------------------------------------------

#define BN_EPS 1e-5f

static __device__ __forceinline__ float bf2f_lo(unsigned u) {
  return __uint_as_float(u << 16);
}
static __device__ __forceinline__ float bf2f_hi(unsigned u) {
  return __uint_as_float(u & 0xffff0000u);
}
static __device__ __forceinline__ ushort f2bf(float x) {
  __hip_bfloat16 b = __float2bfloat16(x);
  return *reinterpret_cast<ushort*>(&b);
}

__global__ __launch_bounds__(256) void hist_kernel(const int* __restrict__ dst,
                                                   int* __restrict__ deg, int E) {
  int i = blockIdx.x * blockDim.x + threadIdx.x;
  int stride = gridDim.x * blockDim.x;
  for (; i < E; i += stride) atomicAdd(&deg[dst[i]], 1);
}

// scan step 1: per-block (1024 elems) exclusive scan + block sum
__global__ __launch_bounds__(256) void scan1_kernel(const int* __restrict__ deg,
                                                    int* __restrict__ rowstart,
                                                    int* __restrict__ partials, int N) {
  __shared__ int wsum[4];
  int tid = threadIdx.x;
  int lane = tid & 63, w = tid >> 6;
  int base = blockIdx.x * 1024 + tid * 4;
  int d0 = 0, d1 = 0, d2 = 0, d3 = 0;
  if (base + 3 < N) {
    int4 v = *reinterpret_cast<const int4*>(deg + base);
    d0 = v.x; d1 = v.y; d2 = v.z; d3 = v.w;
  } else {
    if (base + 0 < N) d0 = deg[base + 0];
    if (base + 1 < N) d1 = deg[base + 1];
    if (base + 2 < N) d2 = deg[base + 2];
  }
  int t0 = d0, t1 = t0 + d1, t2 = t1 + d2, t3 = t2 + d3;
  int tot = t3;
  int inc = tot;
#pragma unroll
  for (int off = 1; off < 64; off <<= 1) {
    int v = __shfl_up(inc, off);
    if (lane >= off) inc += v;
  }
  if (lane == 63) wsum[w] = inc;
  __syncthreads();
  int woff = 0;
  for (int k = 0; k < w; ++k) woff += wsum[k];
  int excl = woff + inc - tot;
  if (base + 0 < N) rowstart[base + 0] = excl;
  if (base + 1 < N) rowstart[base + 1] = excl + t0;
  if (base + 2 < N) rowstart[base + 2] = excl + t1;
  if (base + 3 < N) rowstart[base + 3] = excl + t2;
  if (tid == 255) partials[blockIdx.x] = excl + t3;
}

// scan step 2 (merged): every block wave-scans the <=64 partials; adds its
// offset; mirrors into cursor.  Requires NB <= 64 (N <= 65536).
__global__ __launch_bounds__(256) void scan3_kernel(const int* __restrict__ partials,
                                                    int* __restrict__ rowstart,
                                                    int* __restrict__ cursor,
                                                    int N, int NB, int E) {
  __shared__ int s_off;
  int tid = threadIdx.x;
  if (tid < 64) {
    int v = (tid < NB) ? partials[tid] : 0;
    int inc = v;
#pragma unroll
    for (int off = 1; off < 64; off <<= 1) {
      int t = __shfl_up(inc, off);
      if (tid >= off) inc += t;
    }
    if (tid == (int)blockIdx.x) s_off = inc - v;
  }
  __syncthreads();
  int off = s_off;
  int base = blockIdx.x * 1024 + tid * 4;
#pragma unroll
  for (int k = 0; k < 4; ++k) {
    int i = base + k;
    if (i < N) {
      int r = rowstart[i] + off;
      rowstart[i] = r;
      cursor[i] = r;
    }
  }
  if (blockIdx.x == 0 && tid == 0) rowstart[N] = E;
}

__global__ __launch_bounds__(256) void fill_kernel(const int* __restrict__ src,
                                                   const int* __restrict__ dst,
                                                   int* __restrict__ cursor,
                                                   int2* __restrict__ epack, int E) {
  int i = blockIdx.x * blockDim.x + threadIdx.x;
  int stride = gridDim.x * blockDim.x;
  for (; i < E; i += stride) {
    int p = atomicAdd(&cursor[dst[i]], 1);
    epack[p] = make_int2(src[i], i);  // (src, original edge id) one 8B store
  }
}

// 64-wide GEMM, 64 rows/block, 4x4 microtile per thread over transposed LDS
// activations.  out[n][f] = bias[f] + sum_k T(in[n][k])*W[k][f].
// T = identity or relu(bn) via stats_in.  Optional col stats; optional bf16
// mirror into packed G (row stride 128 ushorts).
__global__ __launch_bounds__(256) void gemm64_kernel(
    const float* __restrict__ in, const float* __restrict__ W,
    const float* __restrict__ bias, const float* __restrict__ stats_in,
    const float* __restrict__ g_in, const float* __restrict__ b_in,
    float* __restrict__ out, float* __restrict__ stats_out,
    ushort* __restrict__ out_g, int N) {
  __shared__ float sW[64][64];
  __shared__ float sxT[64][68];  // [k][row], stride 68 -> 16B-aligned float4 rows
  __shared__ float red[2][16][64];
  int tid = threadIdx.x;
  int lane = tid & 63, w = tid >> 6;
  int n0 = blockIdx.x * 64;
#pragma unroll
  for (int r = 0; r < 16; ++r) {
    int idx = r * 256 + tid;
    sW[idx >> 6][idx & 63] = W[idx];
  }
  float sc = 1.f, sh = 0.f;
  if (stats_in) {
    float invN = 1.0f / (float)N;
    float m = stats_in[lane] * invN;
    float var = stats_in[64 + lane] * invN - m * m;
    sc = g_in[lane] * rsqrtf(var + BN_EPS);
    sh = b_in[lane] - m * sc;
  }
#pragma unroll
  for (int r = 0; r < 16; ++r) {
    int idx = r * 256 + tid;  // (idx&63)==lane
    int row = idx >> 6;       // 0..63
    int n = n0 + row;
    float x = (n < N) ? in[(size_t)n * 64 + lane] : 0.f;
    if (stats_in) x = fmaxf(x * sc + sh, 0.f);
    sxT[lane][row] = x;  // transposed store
  }
  __syncthreads();
  int tc = lane & 15, tr = lane >> 4;
  int rowbase = w * 16 + tr * 4;  // 0..60
  int colbase = tc * 4;
  float acc[16];
  if (bias) {
    float4 bz = *reinterpret_cast<const float4*>(bias + colbase);
#pragma unroll
    for (int rr = 0; rr < 4; ++rr) {
      acc[rr * 4 + 0] = bz.x; acc[rr * 4 + 1] = bz.y;
      acc[rr * 4 + 2] = bz.z; acc[rr * 4 + 3] = bz.w;
    }
  } else {
#pragma unroll
    for (int i = 0; i < 16; ++i) acc[i] = 0.f;
  }
#pragma unroll 8
  for (int k = 0; k < 64; ++k) {
    float4 xv = *reinterpret_cast<const float4*>(&sxT[k][rowbase]);
    float4 wv = *reinterpret_cast<const float4*>(&sW[k][colbase]);
    acc[0]  = fmaf(xv.x, wv.x, acc[0]);  acc[1]  = fmaf(xv.x, wv.y, acc[1]);
    acc[2]  = fmaf(xv.x, wv.z, acc[2]);  acc[3]  = fmaf(xv.x, wv.w, acc[3]);
    acc[4]  = fmaf(xv.y, wv.x, acc[4]);  acc[5]  = fmaf(xv.y, wv.y, acc[5]);
    acc[6]  = fmaf(xv.y, wv.z, acc[6]);  acc[7]  = fmaf(xv.y, wv.w, acc[7]);
    acc[8]  = fmaf(xv.z, wv.x, acc[8]);  acc[9]  = fmaf(xv.z, wv.y, acc[9]);
    acc[10] = fmaf(xv.z, wv.z, acc[10]); acc[11] = fmaf(xv.z, wv.w, acc[11]);
    acc[12] = fmaf(xv.w, wv.x, acc[12]); acc[13] = fmaf(xv.w, wv.y, acc[13]);
    acc[14] = fmaf(xv.w, wv.z, acc[14]); acc[15] = fmaf(xv.w, wv.w, acc[15]);
  }
  float ps[4] = {0.f, 0.f, 0.f, 0.f}, pq[4] = {0.f, 0.f, 0.f, 0.f};
#pragma unroll
  for (int rr = 0; rr < 4; ++rr) {
    int n = n0 + rowbase + rr;
    if (n < N) {
      float4 o = make_float4(acc[rr * 4 + 0], acc[rr * 4 + 1],
                             acc[rr * 4 + 2], acc[rr * 4 + 3]);
      *reinterpret_cast<float4*>(out + (size_t)n * 64 + colbase) = o;
      if (out_g) {
        uint2 pk;
        pk.x = (unsigned)f2bf(o.x) | ((unsigned)f2bf(o.y) << 16);
        pk.y = (unsigned)f2bf(o.z) | ((unsigned)f2bf(o.w) << 16);
        *reinterpret_cast<uint2*>(out_g + (size_t)n * 128 + colbase) = pk;
      }
      ps[0] += o.x; ps[1] += o.y; ps[2] += o.z; ps[3] += o.w;
      pq[0] += o.x * o.x; pq[1] += o.y * o.y;
      pq[2] += o.z * o.z; pq[3] += o.w * o.w;
    }
  }
  if (stats_out) {
    int rg = w * 4 + tr;  // 0..15
#pragma unroll
    for (int cc = 0; cc < 4; ++cc) {
      red[0][rg][colbase + cc] = ps[cc];
      red[1][rg][colbase + cc] = pq[cc];
    }
    __syncthreads();
    if (tid < 128) {
      int s = tid >> 6, col = tid & 63;
      float acc2 = 0.f;
#pragma unroll
      for (int g = 0; g < 16; ++g) acc2 += red[s][g][col];
      atomicAdd(&stats_out[s * 64 + col], acc2);
    }
  }
}

// P1 = T(c)@W1[0:64]+b1 -> packed G (stride 128); P2 = T(c)@W1[64:128] -> [N][64].
// Same 4x4-microtile structure; dual accumulators.
__global__ __launch_bounds__(256) void proj_kernel(
    const float* __restrict__ c, const float* __restrict__ W1,
    const float* __restrict__ b1, const float* __restrict__ stats_in,
    const float* __restrict__ g_in, const float* __restrict__ b_in,
    ushort* __restrict__ G, ushort* __restrict__ P2, int N) {
  __shared__ float sWa[64][64];
  __shared__ float sWb[64][64];
  __shared__ float sxT[64][68];
  int tid = threadIdx.x, lane = tid & 63, w = tid >> 6;
  int n0 = blockIdx.x * 64;
#pragma unroll
  for (int r = 0; r < 16; ++r) {
    int idx = r * 256 + tid;
    sWa[idx >> 6][idx & 63] = W1[idx];
    sWb[idx >> 6][idx & 63] = W1[4096 + idx];
  }
  float sc = 1.f, sh = 0.f;
  if (stats_in) {
    float invN = 1.0f / (float)N;
    float m = stats_in[lane] * invN;
    float var = stats_in[64 + lane] * invN - m * m;
    sc = g_in[lane] * rsqrtf(var + BN_EPS);
    sh = b_in[lane] - m * sc;
  }
#pragma unroll
  for (int r = 0; r < 16; ++r) {
    int idx = r * 256 + tid;
    int row = idx >> 6;
    int n = n0 + row;
    float x = (n < N) ? c[(size_t)n * 64 + lane] : 0.f;
    if (stats_in) x = fmaxf(x * sc + sh, 0.f);
    sxT[lane][row] = x;
  }
  __syncthreads();
  int tc = lane & 15, tr = lane >> 4;
  int rowbase = w * 16 + tr * 4;
  int colbase = tc * 4;
  float a1[16], a2[16];
  {
    float4 bz = *reinterpret_cast<const float4*>(b1 + colbase);
#pragma unroll
    for (int rr = 0; rr < 4; ++rr) {
      a1[rr * 4 + 0] = bz.x; a1[rr * 4 + 1] = bz.y;
      a1[rr * 4 + 2] = bz.z; a1[rr * 4 + 3] = bz.w;
    }
#pragma unroll
    for (int i = 0; i < 16; ++i) a2[i] = 0.f;
  }
#pragma unroll 4
  for (int k = 0; k < 64; ++k) {
    float4 xv = *reinterpret_cast<const float4*>(&sxT[k][rowbase]);
    float4 wa = *reinterpret_cast<const float4*>(&sWa[k][colbase]);
    float4 wb = *reinterpret_cast<const float4*>(&sWb[k][colbase]);
    a1[0]  = fmaf(xv.x, wa.x, a1[0]);  a1[1]  = fmaf(xv.x, wa.y, a1[1]);
    a1[2]  = fmaf(xv.x, wa.z, a1[2]);  a1[3]  = fmaf(xv.x, wa.w, a1[3]);
    a1[4]  = fmaf(xv.y, wa.x, a1[4]);  a1[5]  = fmaf(xv.y, wa.y, a1[5]);
    a1[6]  = fmaf(xv.y, wa.z, a1[6]);  a1[7]  = fmaf(xv.y, wa.w, a1[7]);
    a1[8]  = fmaf(xv.z, wa.x, a1[8]);  a1[9]  = fmaf(xv.z, wa.y, a1[9]);
    a1[10] = fmaf(xv.z, wa.z, a1[10]); a1[11] = fmaf(xv.z, wa.w, a1[11]);
    a1[12] = fmaf(xv.w, wa.x, a1[12]); a1[13] = fmaf(xv.w, wa.y, a1[13]);
    a1[14] = fmaf(xv.w, wa.z, a1[14]); a1[15] = fmaf(xv.w, wa.w, a1[15]);
    a2[0]  = fmaf(xv.x, wb.x, a2[0]);  a2[1]  = fmaf(xv.x, wb.y, a2[1]);
    a2[2]  = fmaf(xv.x, wb.z, a2[2]);  a2[3]  = fmaf(xv.x, wb.w, a2[3]);
    a2[4]  = fmaf(xv.y, wb.x, a2[4]);  a2[5]  = fmaf(xv.y, wb.y, a2[5]);
    a2[6]  = fmaf(xv.y, wb.z, a2[6]);  a2[7]  = fmaf(xv.y, wb.w, a2[7]);
    a2[8]  = fmaf(xv.z, wb.x, a2[8]);  a2[9]  = fmaf(xv.z, wb.y, a2[9]);
    a2[10] = fmaf(xv.z, wb.z, a2[10]); a2[11] = fmaf(xv.z, wb.w, a2[11]);
    a2[12] = fmaf(xv.w, wb.x, a2[12]); a2[13] = fmaf(xv.w, wb.y, a2[13]);
    a2[14] = fmaf(xv.w, wb.z, a2[14]); a2[15] = fmaf(xv.w, wb.w, a2[15]);
  }
#pragma unroll
  for (int rr = 0; rr < 4; ++rr) {
    int n = n0 + rowbase + rr;
    if (n < N) {
      uint2 p1k, p2k;
      p1k.x = (unsigned)f2bf(a1[rr * 4 + 0]) | ((unsigned)f2bf(a1[rr * 4 + 1]) << 16);
      p1k.y = (unsigned)f2bf(a1[rr * 4 + 2]) | ((unsigned)f2bf(a1[rr * 4 + 3]) << 16);
      p2k.x = (unsigned)f2bf(a2[rr * 4 + 0]) | ((unsigned)f2bf(a2[rr * 4 + 1]) << 16);
      p2k.y = (unsigned)f2bf(a2[rr * 4 + 2]) | ((unsigned)f2bf(a2[rr * 4 + 3]) << 16);
      *reinterpret_cast<uint2*>(G + (size_t)n * 128 + colbase) = p1k;
      *reinterpret_cast<uint2*>(P2 + (size_t)n * 64 + colbase) = p2k;
    }
  }
}

// c = relu(bn(in)); col stats of c; bf16 mirror into packed G (offset 64).
__global__ __launch_bounds__(256) void bnrelu_kernel(
    const float* __restrict__ in, const float* __restrict__ stats_in,
    const float* __restrict__ g_in, const float* __restrict__ b_in,
    float* __restrict__ out, float* __restrict__ stats_out,
    ushort* __restrict__ out_g, int N) {
  __shared__ float red[2][4][64];
  int tid = threadIdx.x;
  int lane = tid & 63, w = tid >> 6;
  float invN = 1.0f / (float)N;
  float m = stats_in[lane] * invN;
  float var = stats_in[64 + lane] * invN - m * m;
  float sc = g_in[lane] * rsqrtf(var + BN_EPS);
  float sh = b_in[lane] - m * sc;
  float ps = 0.f, pq = 0.f;
  int rows_per_grid = gridDim.x * (blockDim.x >> 6);
  for (int n = blockIdx.x * (blockDim.x >> 6) + w; n < N; n += rows_per_grid) {
    float x = fmaxf(in[(size_t)n * 64 + lane] * sc + sh, 0.f);
    out[(size_t)n * 64 + lane] = x;
    out_g[(size_t)n * 128 + lane] = f2bf(x);
    ps += x;
    pq += x * x;
  }
  if (stats_out) {
    red[0][w][lane] = ps;
    red[1][w][lane] = pq;
    __syncthreads();
    if (w == 0) {
      float s = red[0][0][lane] + red[0][1][lane] + red[0][2][lane] + red[0][3][lane];
      float q = red[1][0][lane] + red[1][1][lane] + red[1][2][lane] + red[1][3][lane];
      atomicAdd(&stats_out[lane], s);
      atomicAdd(&stats_out[64 + lane], q);
    }
  }
}

// FUSED per-layer edge walk: wave per dst node v; 4 groups x 16 lanes.
// Each group processes one edge per iter, loading the packed 256B record
// G[s] = [P1 row | cb row]:
//   lanes g16<8 : score  sc[p] (+)= relu(P1[s]+P2[v]) @ W2 + b2
//   lanes g16>=8: agg    acc += T(cb[s])   (T = relu-affine if TR)
// Epilogue: zb[v] = T(c[v]) + cross-group-reduced acc.
template <int TR>
__global__ __launch_bounds__(256) void score_agg_kernel(
    const ushort* __restrict__ G, const ushort* __restrict__ P2,
    const float* __restrict__ c, const int* __restrict__ rowstart,
    const int2* __restrict__ epack, const float* __restrict__ W2,
    const float* __restrict__ b2, const float* __restrict__ stats_tr,
    const float* __restrict__ g_tr, const float* __restrict__ b_tr,
    float2* __restrict__ sc, float* __restrict__ zb, int N, int first) {
  int lane = threadIdx.x & 63;
  int v = blockIdx.x * 4 + (threadIdx.x >> 6);
  if (v >= N) return;
  int grp = lane >> 4;  // 0..3 : edge slot
  int g16 = lane & 15;  // role within group
  int sub = g16 & 7;
  float w[16];
  {
    const float4* wp = reinterpret_cast<const float4*>(W2 + sub * 16);
#pragma unroll
    for (int k = 0; k < 4; ++k) {
      float4 t = wp[k];
      w[4 * k + 0] = t.x; w[4 * k + 1] = t.y; w[4 * k + 2] = t.z; w[4 * k + 3] = t.w;
    }
  }
  float bb0 = b2[0], bb1 = b2[1];
  uint4 pb = *reinterpret_cast<const uint4*>(P2 + (size_t)v * 64 + sub * 8);
  unsigned bv[4] = {pb.x, pb.y, pb.z, pb.w};
  float scv[8], shv[8];
  if (TR) {
    float invN = 1.0f / (float)N;
#pragma unroll
    for (int k = 0; k < 8; ++k) {
      int f = sub * 8 + k;
      float m = stats_tr[f] * invN;
      float var = stats_tr[64 + f] * invN - m * m;
      scv[k] = g_tr[f] * rsqrtf(var + BN_EPS);
      shv[k] = b_tr[f] - m * scv[k];
    }
  }
  float acc[8];
#pragma unroll
  for (int k = 0; k < 8; ++k) acc[k] = 0.f;

  int p0 = rowstart[v], p1 = rowstart[v + 1];
  for (int p = p0 + grp; p < p1; p += 4) {
    int s = epack[p].x;
    uint4 row = *reinterpret_cast<const uint4*>(G + (size_t)s * 128 + g16 * 8);
    unsigned rv[4] = {row.x, row.y, row.z, row.w};
    float q0 = 0.f, q1 = 0.f;
    if (g16 < 8) {
#pragma unroll
      for (int k = 0; k < 4; ++k) {
        float v0 = fmaxf(bf2f_lo(rv[k]) + bf2f_lo(bv[k]), 0.f);
        float v1 = fmaxf(bf2f_hi(rv[k]) + bf2f_hi(bv[k]), 0.f);
        q0 = fmaf(v0, w[4 * k + 0], fmaf(v1, w[4 * k + 2], q0));
        q1 = fmaf(v0, w[4 * k + 1], fmaf(v1, w[4 * k + 3], q1));
      }
    } else {
#pragma unroll
      for (int k = 0; k < 4; ++k) {
        float x0 = bf2f_lo(rv[k]);
        float x1 = bf2f_hi(rv[k]);
        if (TR) {
          x0 = fmaxf(x0 * scv[2 * k] + shv[2 * k], 0.f);
          x1 = fmaxf(x1 * scv[2 * k + 1] + shv[2 * k + 1], 0.f);
        }
        acc[2 * k] += x0;
        acc[2 * k + 1] += x1;
      }
    }
#pragma unroll
    for (int mm = 1; mm < 8; mm <<= 1) {
      q0 += __shfl_xor(q0, mm);
      q1 += __shfl_xor(q1, mm);
    }
    if (g16 == 0) {
      float o0 = q0 + bb0, o1 = q1 + bb1;
      if (!first) {
        float2 prev = sc[p];
        o0 += prev.x;
        o1 += prev.y;
      }
      sc[p] = make_float2(o0, o1);
    }
  }
#pragma unroll
  for (int k = 0; k < 8; ++k) {
    acc[k] += __shfl_xor(acc[k], 16);
    acc[k] += __shfl_xor(acc[k], 32);
  }
  if (grp == 0 && g16 >= 8) {
    const float* cv = c + (size_t)v * 64 + sub * 8;
    float4 c0 = *reinterpret_cast<const float4*>(cv);
    float4 c1 = *reinterpret_cast<const float4*>(cv + 4);
    float cf[8] = {c0.x, c0.y, c0.z, c0.w, c1.x, c1.y, c1.z, c1.w};
    float ov[8];
#pragma unroll
    for (int k = 0; k < 8; ++k) {
      float x = cf[k];
      if (TR) x = fmaxf(x * scv[k] + shv[k], 0.f);
      ov[k] = acc[k] + x;
    }
    float* zp = zb + (size_t)v * 64 + sub * 8;
    *reinterpret_cast<float4*>(zp) = make_float4(ov[0], ov[1], ov[2], ov[3]);
    *reinterpret_cast<float4*>(zp + 4) = make_float4(ov[4], ov[5], ov[6], ov[7]);
  }
}

// score-only CSR walk for the LAST rep: adds prev accumulation from sc[] and
// writes final score directly to out[orig edge id] (no separate scatter).
__global__ __launch_bounds__(256) void edge_score_final_kernel(
    const ushort* __restrict__ G, const ushort* __restrict__ P2,
    const int* __restrict__ rowstart, const int2* __restrict__ epack,
    const float* __restrict__ W2, const float* __restrict__ b2,
    const float2* __restrict__ sc, float2* __restrict__ out, int N) {
  int lane = threadIdx.x & 63;
  int v = blockIdx.x * 4 + (threadIdx.x >> 6);
  if (v >= N) return;
  int sub = lane & 7;
  int grp = lane >> 3;
  float w[16];
  const float4* wp = reinterpret_cast<const float4*>(W2 + sub * 16);
#pragma unroll
  for (int k = 0; k < 4; ++k) {
    float4 t = wp[k];
    w[4 * k + 0] = t.x; w[4 * k + 1] = t.y; w[4 * k + 2] = t.z; w[4 * k + 3] = t.w;
  }
  float bb0 = b2[0], bb1 = b2[1];
  uint4 pb = *reinterpret_cast<const uint4*>(P2 + (size_t)v * 64 + sub * 8);
  unsigned bv[4] = {pb.x, pb.y, pb.z, pb.w};
  int p0 = rowstart[v], p1 = rowstart[v + 1];
  for (int p = p0 + grp; p < p1; p += 8) {
    int2 ep = epack[p];
    int s = ep.x;
    uint4 pa = *reinterpret_cast<const uint4*>(G + (size_t)s * 128 + sub * 8);
    unsigned av[4] = {pa.x, pa.y, pa.z, pa.w};
    float q0 = 0.f, q1 = 0.f;
#pragma unroll
    for (int k = 0; k < 4; ++k) {
      float v0 = fmaxf(bf2f_lo(av[k]) + bf2f_lo(bv[k]), 0.f);
      float v1 = fmaxf(bf2f_hi(av[k]) + bf2f_hi(bv[k]), 0.f);
      q0 = fmaf(v0, w[4 * k + 0], fmaf(v1, w[4 * k + 2], q0));
      q1 = fmaf(v0, w[4 * k + 1], fmaf(v1, w[4 * k + 3], q1));
    }
#pragma unroll
    for (int mm = 1; mm < 8; mm <<= 1) {
      q0 += __shfl_xor(q0, mm);
      q1 += __shfl_xor(q1, mm);
    }
    if (sub == 0) {
      float2 prev = sc[p];
      out[ep.y] = make_float2(q0 + bb0 + prev.x, q1 + bb1 + prev.y);
    }
  }
}

extern "C" void kernel_launch(void* const* d_in, const int* in_sizes, int n_in,
                              void* d_out, int out_size, void* d_ws, size_t ws_size,
                              hipStream_t stream) {
  const float* h          = (const float*)d_in[0];
  const int*   src        = (const int*)d_in[1];
  const int*   dst        = (const int*)d_in[2];
  const float* emb_W      = (const float*)d_in[3];
  const float* emb_b      = (const float*)d_in[4];
  const float* mlp_W1     = (const float*)d_in[5];
  const float* mlp_b1     = (const float*)d_in[6];
  const float* mlp_bn_g   = (const float*)d_in[7];
  const float* mlp_bn_b   = (const float*)d_in[8];
  const float* mlp_W2     = (const float*)d_in[9];
  const float* mlp_b2     = (const float*)d_in[10];
  const float* apply_bn_g = (const float*)d_in[11];
  const float* apply_bn_b = (const float*)d_in[12];
  const float* out_bn_g   = (const float*)d_in[13];
  const float* out_bn_b   = (const float*)d_in[14];
  const float* pred_W1    = (const float*)d_in[15];
  const float* pred_b1    = (const float*)d_in[16];
  const float* pred_W2    = (const float*)d_in[17];
  const float* pred_b2    = (const float*)d_in[18];

  const int N = in_sizes[0] / 64;
  const int E = in_sizes[1];
  const size_t NF = (size_t)N * 64;
  const int NB1 = (N + 1023) / 1024;  // scan3 requires NB1 <= 64 (N <= 65536)

  float* ws = (float*)d_ws;
  float* c   = ws;            // current node features (f32), pre-bn_out
  float* z1  = c + NF;
  float* zb  = z1 + NF;       // agg output; ALSO reused as z2 (disjoint lifetime)
  ushort* G  = (ushort*)(zb + NF);  // packed [N][128]: [0..63]=P1, [64..127]=cb
  ushort* P2 = G + (size_t)N * 128;
  int2*   epack = (int2*)(P2 + NF); // (src, orig edge id) per CSR slot
  float2* scbuf = (float2*)(epack + E);
  int* rowstart = (int*)(scbuf + E);          // N+1 (padded)
  int* cursor   = rowstart + (N + 64);
  int* partials = cursor + (N + 64);          // 64
  int* deg      = partials + 64;
  float* stats  = (float*)(deg + (N + 64));   // 9 slots x [sum(64), sumsq(64)]

  size_t need = (size_t)((char*)(stats + 9 * 128) - (char*)d_ws);
  if (need > ws_size) return;

  hipMemsetAsync(deg, 0, ((size_t)(N + 64) + 9 * 128) * sizeof(int), stream);

  const int gemmBlocks = (N + 63) / 64;
  const int nodeBlocks = (N + 3) / 4;

  // embedding: c = h @ emb_W + emb_b  (+ cb into packed G)
  gemm64_kernel<<<gemmBlocks, 256, 0, stream>>>(h, emb_W, emb_b, nullptr, nullptr,
                                                nullptr, c, nullptr, G + 64, N);
  // CSR build (by dst)
  hist_kernel<<<1024, 256, 0, stream>>>(dst, deg, E);
  scan1_kernel<<<NB1, 256, 0, stream>>>(deg, rowstart, partials, N);
  scan3_kernel<<<NB1, 256, 0, stream>>>(partials, rowstart, cursor, N, NB1, E);
  fill_kernel<<<1024, 256, 0, stream>>>(src, dst, cursor, epack, E);

  // rep 0: proj (identity) then fused score0 + agg(layer0)
  proj_kernel<<<gemmBlocks, 256, 0, stream>>>(c, pred_W1, pred_b1, nullptr, nullptr,
                                              nullptr, G, P2, N);
  score_agg_kernel<0><<<nodeBlocks, 256, 0, stream>>>(
      G, P2, c, rowstart, epack, pred_W2, pred_b2, nullptr, nullptr, nullptr,
      scbuf, zb, N, 1);

  for (int i = 0; i < 3; ++i) {
    float* st1 = stats + (size_t)(3 * i + 0) * 128;
    float* st2 = stats + (size_t)(3 * i + 1) * 128;
    float* st3 = stats + (size_t)(3 * i + 2) * 128;

    // z1 = zb @ W1 + b1  (+ stats st1)
    gemm64_kernel<<<gemmBlocks, 256, 0, stream>>>(zb, mlp_W1 + (size_t)i * 4096,
                                                  mlp_b1 + i * 64, nullptr, nullptr,
                                                  nullptr, z1, st1, nullptr, N);
    // z2(=zb) = relu(bn_mlp(z1)) @ W2 + b2  (+ stats st2)
    gemm64_kernel<<<gemmBlocks, 256, 0, stream>>>(z1, mlp_W2 + (size_t)i * 4096,
                                                  mlp_b2 + i * 64, st1,
                                                  mlp_bn_g + i * 64, mlp_bn_b + i * 64,
                                                  zb, st2, nullptr, N);
    // c = relu(bn_apply(z2))  (+ stats st3, cb into packed G); bn_out deferred
    bnrelu_kernel<<<784, 256, 0, stream>>>(zb, st2, apply_bn_g + i * 64,
                                           apply_bn_b + i * 64, c, st3, G + 64, N);
    // proj rep i+1 (applies deferred bn_out[i] via st3)
    proj_kernel<<<gemmBlocks, 256, 0, stream>>>(c, pred_W1 + (size_t)(i + 1) * 8192,
                                                pred_b1 + (i + 1) * 64, st3,
                                                out_bn_g + i * 64, out_bn_b + i * 64,
                                                G, P2, N);
    if (i < 2) {
      // fused: score rep i+1 + agg for layer i+1 (affine T via st3/out_bn)
      score_agg_kernel<1><<<nodeBlocks, 256, 0, stream>>>(
          G, P2, c, rowstart, epack, pred_W2 + (i + 1) * 128,
          pred_b2 + (i + 1) * 2, st3, out_bn_g + i * 64, out_bn_b + i * 64,
          scbuf, zb, N, 0);
    } else {
      // last rep: score only, write final result straight to d_out[eord]
      edge_score_final_kernel<<<nodeBlocks, 256, 0, stream>>>(
          G, P2, rowstart, epack, pred_W2 + (i + 1) * 128,
          pred_b2 + (i + 1) * 2, scbuf, (float2*)d_out, N);
    }
  }
}

// Round 11
// 832.967 us; speedup vs baseline: 1.3617x; 1.0123x over previous
//
#include <hip/hip_runtime.h>
#include <hip/hip_bf16.h>

// ---------------------------------------------------------------------------
// GINEdge: 3-layer GIN (sum agg) + per-layer edge MLP scoring.
//   relu([h_s,h_d]@W1+b1)@W2 == relu(P1[s]+P2[d])@W2,
//   P1 = h@W1[:64] + b1, P2 = h@W1[64:]  (per-node projections).
// R11 changes vs R10:
//   - score_agg de-diverged: 8 groups x 8 lanes; per edge, ALL lanes run
//     score phase then agg phase (both 16B record halves loaded up front).
//     Was: 16-lane groups with if(g16<8) role split -> serialized halves.
// gemm/proj 4x4-microtile, CSR build, final-walk-direct-write: unchanged.
// ---------------------------------------------------------------------------

#define BN_EPS 1e-5f

static __device__ __forceinline__ float bf2f_lo(unsigned u) {
  return __uint_as_float(u << 16);
}
static __device__ __forceinline__ float bf2f_hi(unsigned u) {
  return __uint_as_float(u & 0xffff0000u);
}
static __device__ __forceinline__ ushort f2bf(float x) {
  __hip_bfloat16 b = __float2bfloat16(x);
  return *reinterpret_cast<ushort*>(&b);
}

__global__ __launch_bounds__(256) void hist_kernel(const int* __restrict__ dst,
                                                   int* __restrict__ deg, int E) {
  int i = blockIdx.x * blockDim.x + threadIdx.x;
  int stride = gridDim.x * blockDim.x;
  for (; i < E; i += stride) atomicAdd(&deg[dst[i]], 1);
}

// scan step 1: per-block (1024 elems) exclusive scan + block sum
__global__ __launch_bounds__(256) void scan1_kernel(const int* __restrict__ deg,
                                                    int* __restrict__ rowstart,
                                                    int* __restrict__ partials, int N) {
  __shared__ int wsum[4];
  int tid = threadIdx.x;
  int lane = tid & 63, w = tid >> 6;
  int base = blockIdx.x * 1024 + tid * 4;
  int d0 = 0, d1 = 0, d2 = 0, d3 = 0;
  if (base + 3 < N) {
    int4 v = *reinterpret_cast<const int4*>(deg + base);
    d0 = v.x; d1 = v.y; d2 = v.z; d3 = v.w;
  } else {
    if (base + 0 < N) d0 = deg[base + 0];
    if (base + 1 < N) d1 = deg[base + 1];
    if (base + 2 < N) d2 = deg[base + 2];
  }
  int t0 = d0, t1 = t0 + d1, t2 = t1 + d2, t3 = t2 + d3;
  int tot = t3;
  int inc = tot;
#pragma unroll
  for (int off = 1; off < 64; off <<= 1) {
    int v = __shfl_up(inc, off);
    if (lane >= off) inc += v;
  }
  if (lane == 63) wsum[w] = inc;
  __syncthreads();
  int woff = 0;
  for (int k = 0; k < w; ++k) woff += wsum[k];
  int excl = woff + inc - tot;
  if (base + 0 < N) rowstart[base + 0] = excl;
  if (base + 1 < N) rowstart[base + 1] = excl + t0;
  if (base + 2 < N) rowstart[base + 2] = excl + t1;
  if (base + 3 < N) rowstart[base + 3] = excl + t2;
  if (tid == 255) partials[blockIdx.x] = excl + t3;
}

// scan step 2 (merged): every block wave-scans the <=64 partials; adds its
// offset; mirrors into cursor.  Requires NB <= 64 (N <= 65536).
__global__ __launch_bounds__(256) void scan3_kernel(const int* __restrict__ partials,
                                                    int* __restrict__ rowstart,
                                                    int* __restrict__ cursor,
                                                    int N, int NB, int E) {
  __shared__ int s_off;
  int tid = threadIdx.x;
  if (tid < 64) {
    int v = (tid < NB) ? partials[tid] : 0;
    int inc = v;
#pragma unroll
    for (int off = 1; off < 64; off <<= 1) {
      int t = __shfl_up(inc, off);
      if (tid >= off) inc += t;
    }
    if (tid == (int)blockIdx.x) s_off = inc - v;
  }
  __syncthreads();
  int off = s_off;
  int base = blockIdx.x * 1024 + tid * 4;
#pragma unroll
  for (int k = 0; k < 4; ++k) {
    int i = base + k;
    if (i < N) {
      int r = rowstart[i] + off;
      rowstart[i] = r;
      cursor[i] = r;
    }
  }
  if (blockIdx.x == 0 && tid == 0) rowstart[N] = E;
}

__global__ __launch_bounds__(256) void fill_kernel(const int* __restrict__ src,
                                                   const int* __restrict__ dst,
                                                   int* __restrict__ cursor,
                                                   int2* __restrict__ epack, int E) {
  int i = blockIdx.x * blockDim.x + threadIdx.x;
  int stride = gridDim.x * blockDim.x;
  for (; i < E; i += stride) {
    int p = atomicAdd(&cursor[dst[i]], 1);
    epack[p] = make_int2(src[i], i);  // (src, original edge id) one 8B store
  }
}

// 64-wide GEMM, 64 rows/block, 4x4 microtile per thread over transposed LDS
// activations.  out[n][f] = bias[f] + sum_k T(in[n][k])*W[k][f].
// T = identity or relu(bn) via stats_in.  Optional col stats; optional bf16
// mirror into packed G (row stride 128 ushorts).
__global__ __launch_bounds__(256) void gemm64_kernel(
    const float* __restrict__ in, const float* __restrict__ W,
    const float* __restrict__ bias, const float* __restrict__ stats_in,
    const float* __restrict__ g_in, const float* __restrict__ b_in,
    float* __restrict__ out, float* __restrict__ stats_out,
    ushort* __restrict__ out_g, int N) {
  __shared__ float sW[64][64];
  __shared__ float sxT[64][68];  // [k][row], stride 68 -> 16B-aligned float4 rows
  __shared__ float red[2][16][64];
  int tid = threadIdx.x;
  int lane = tid & 63, w = tid >> 6;
  int n0 = blockIdx.x * 64;
#pragma unroll
  for (int r = 0; r < 16; ++r) {
    int idx = r * 256 + tid;
    sW[idx >> 6][idx & 63] = W[idx];
  }
  float sc = 1.f, sh = 0.f;
  if (stats_in) {
    float invN = 1.0f / (float)N;
    float m = stats_in[lane] * invN;
    float var = stats_in[64 + lane] * invN - m * m;
    sc = g_in[lane] * rsqrtf(var + BN_EPS);
    sh = b_in[lane] - m * sc;
  }
#pragma unroll
  for (int r = 0; r < 16; ++r) {
    int idx = r * 256 + tid;  // (idx&63)==lane
    int row = idx >> 6;       // 0..63
    int n = n0 + row;
    float x = (n < N) ? in[(size_t)n * 64 + lane] : 0.f;
    if (stats_in) x = fmaxf(x * sc + sh, 0.f);
    sxT[lane][row] = x;  // transposed store
  }
  __syncthreads();
  int tc = lane & 15, tr = lane >> 4;
  int rowbase = w * 16 + tr * 4;  // 0..60
  int colbase = tc * 4;
  float acc[16];
  if (bias) {
    float4 bz = *reinterpret_cast<const float4*>(bias + colbase);
#pragma unroll
    for (int rr = 0; rr < 4; ++rr) {
      acc[rr * 4 + 0] = bz.x; acc[rr * 4 + 1] = bz.y;
      acc[rr * 4 + 2] = bz.z; acc[rr * 4 + 3] = bz.w;
    }
  } else {
#pragma unroll
    for (int i = 0; i < 16; ++i) acc[i] = 0.f;
  }
#pragma unroll 8
  for (int k = 0; k < 64; ++k) {
    float4 xv = *reinterpret_cast<const float4*>(&sxT[k][rowbase]);
    float4 wv = *reinterpret_cast<const float4*>(&sW[k][colbase]);
    acc[0]  = fmaf(xv.x, wv.x, acc[0]);  acc[1]  = fmaf(xv.x, wv.y, acc[1]);
    acc[2]  = fmaf(xv.x, wv.z, acc[2]);  acc[3]  = fmaf(xv.x, wv.w, acc[3]);
    acc[4]  = fmaf(xv.y, wv.x, acc[4]);  acc[5]  = fmaf(xv.y, wv.y, acc[5]);
    acc[6]  = fmaf(xv.y, wv.z, acc[6]);  acc[7]  = fmaf(xv.y, wv.w, acc[7]);
    acc[8]  = fmaf(xv.z, wv.x, acc[8]);  acc[9]  = fmaf(xv.z, wv.y, acc[9]);
    acc[10] = fmaf(xv.z, wv.z, acc[10]); acc[11] = fmaf(xv.z, wv.w, acc[11]);
    acc[12] = fmaf(xv.w, wv.x, acc[12]); acc[13] = fmaf(xv.w, wv.y, acc[13]);
    acc[14] = fmaf(xv.w, wv.z, acc[14]); acc[15] = fmaf(xv.w, wv.w, acc[15]);
  }
  float ps[4] = {0.f, 0.f, 0.f, 0.f}, pq[4] = {0.f, 0.f, 0.f, 0.f};
#pragma unroll
  for (int rr = 0; rr < 4; ++rr) {
    int n = n0 + rowbase + rr;
    if (n < N) {
      float4 o = make_float4(acc[rr * 4 + 0], acc[rr * 4 + 1],
                             acc[rr * 4 + 2], acc[rr * 4 + 3]);
      *reinterpret_cast<float4*>(out + (size_t)n * 64 + colbase) = o;
      if (out_g) {
        uint2 pk;
        pk.x = (unsigned)f2bf(o.x) | ((unsigned)f2bf(o.y) << 16);
        pk.y = (unsigned)f2bf(o.z) | ((unsigned)f2bf(o.w) << 16);
        *reinterpret_cast<uint2*>(out_g + (size_t)n * 128 + colbase) = pk;
      }
      ps[0] += o.x; ps[1] += o.y; ps[2] += o.z; ps[3] += o.w;
      pq[0] += o.x * o.x; pq[1] += o.y * o.y;
      pq[2] += o.z * o.z; pq[3] += o.w * o.w;
    }
  }
  if (stats_out) {
    int rg = w * 4 + tr;  // 0..15
#pragma unroll
    for (int cc = 0; cc < 4; ++cc) {
      red[0][rg][colbase + cc] = ps[cc];
      red[1][rg][colbase + cc] = pq[cc];
    }
    __syncthreads();
    if (tid < 128) {
      int s = tid >> 6, col = tid & 63;
      float acc2 = 0.f;
#pragma unroll
      for (int g = 0; g < 16; ++g) acc2 += red[s][g][col];
      atomicAdd(&stats_out[s * 64 + col], acc2);
    }
  }
}

// P1 = T(c)@W1[0:64]+b1 -> packed G (stride 128); P2 = T(c)@W1[64:128] -> [N][64].
// Same 4x4-microtile structure; dual accumulators.
__global__ __launch_bounds__(256) void proj_kernel(
    const float* __restrict__ c, const float* __restrict__ W1,
    const float* __restrict__ b1, const float* __restrict__ stats_in,
    const float* __restrict__ g_in, const float* __restrict__ b_in,
    ushort* __restrict__ G, ushort* __restrict__ P2, int N) {
  __shared__ float sWa[64][64];
  __shared__ float sWb[64][64];
  __shared__ float sxT[64][68];
  int tid = threadIdx.x, lane = tid & 63, w = tid >> 6;
  int n0 = blockIdx.x * 64;
#pragma unroll
  for (int r = 0; r < 16; ++r) {
    int idx = r * 256 + tid;
    sWa[idx >> 6][idx & 63] = W1[idx];
    sWb[idx >> 6][idx & 63] = W1[4096 + idx];
  }
  float sc = 1.f, sh = 0.f;
  if (stats_in) {
    float invN = 1.0f / (float)N;
    float m = stats_in[lane] * invN;
    float var = stats_in[64 + lane] * invN - m * m;
    sc = g_in[lane] * rsqrtf(var + BN_EPS);
    sh = b_in[lane] - m * sc;
  }
#pragma unroll
  for (int r = 0; r < 16; ++r) {
    int idx = r * 256 + tid;
    int row = idx >> 6;
    int n = n0 + row;
    float x = (n < N) ? c[(size_t)n * 64 + lane] : 0.f;
    if (stats_in) x = fmaxf(x * sc + sh, 0.f);
    sxT[lane][row] = x;
  }
  __syncthreads();
  int tc = lane & 15, tr = lane >> 4;
  int rowbase = w * 16 + tr * 4;
  int colbase = tc * 4;
  float a1[16], a2[16];
  {
    float4 bz = *reinterpret_cast<const float4*>(b1 + colbase);
#pragma unroll
    for (int rr = 0; rr < 4; ++rr) {
      a1[rr * 4 + 0] = bz.x; a1[rr * 4 + 1] = bz.y;
      a1[rr * 4 + 2] = bz.z; a1[rr * 4 + 3] = bz.w;
    }
#pragma unroll
    for (int i = 0; i < 16; ++i) a2[i] = 0.f;
  }
#pragma unroll 4
  for (int k = 0; k < 64; ++k) {
    float4 xv = *reinterpret_cast<const float4*>(&sxT[k][rowbase]);
    float4 wa = *reinterpret_cast<const float4*>(&sWa[k][colbase]);
    float4 wb = *reinterpret_cast<const float4*>(&sWb[k][colbase]);
    a1[0]  = fmaf(xv.x, wa.x, a1[0]);  a1[1]  = fmaf(xv.x, wa.y, a1[1]);
    a1[2]  = fmaf(xv.x, wa.z, a1[2]);  a1[3]  = fmaf(xv.x, wa.w, a1[3]);
    a1[4]  = fmaf(xv.y, wa.x, a1[4]);  a1[5]  = fmaf(xv.y, wa.y, a1[5]);
    a1[6]  = fmaf(xv.y, wa.z, a1[6]);  a1[7]  = fmaf(xv.y, wa.w, a1[7]);
    a1[8]  = fmaf(xv.z, wa.x, a1[8]);  a1[9]  = fmaf(xv.z, wa.y, a1[9]);
    a1[10] = fmaf(xv.z, wa.z, a1[10]); a1[11] = fmaf(xv.z, wa.w, a1[11]);
    a1[12] = fmaf(xv.w, wa.x, a1[12]); a1[13] = fmaf(xv.w, wa.y, a1[13]);
    a1[14] = fmaf(xv.w, wa.z, a1[14]); a1[15] = fmaf(xv.w, wa.w, a1[15]);
    a2[0]  = fmaf(xv.x, wb.x, a2[0]);  a2[1]  = fmaf(xv.x, wb.y, a2[1]);
    a2[2]  = fmaf(xv.x, wb.z, a2[2]);  a2[3]  = fmaf(xv.x, wb.w, a2[3]);
    a2[4]  = fmaf(xv.y, wb.x, a2[4]);  a2[5]  = fmaf(xv.y, wb.y, a2[5]);
    a2[6]  = fmaf(xv.y, wb.z, a2[6]);  a2[7]  = fmaf(xv.y, wb.w, a2[7]);
    a2[8]  = fmaf(xv.z, wb.x, a2[8]);  a2[9]  = fmaf(xv.z, wb.y, a2[9]);
    a2[10] = fmaf(xv.z, wb.z, a2[10]); a2[11] = fmaf(xv.z, wb.w, a2[11]);
    a2[12] = fmaf(xv.w, wb.x, a2[12]); a2[13] = fmaf(xv.w, wb.y, a2[13]);
    a2[14] = fmaf(xv.w, wb.z, a2[14]); a2[15] = fmaf(xv.w, wb.w, a2[15]);
  }
#pragma unroll
  for (int rr = 0; rr < 4; ++rr) {
    int n = n0 + rowbase + rr;
    if (n < N) {
      uint2 p1k, p2k;
      p1k.x = (unsigned)f2bf(a1[rr * 4 + 0]) | ((unsigned)f2bf(a1[rr * 4 + 1]) << 16);
      p1k.y = (unsigned)f2bf(a1[rr * 4 + 2]) | ((unsigned)f2bf(a1[rr * 4 + 3]) << 16);
      p2k.x = (unsigned)f2bf(a2[rr * 4 + 0]) | ((unsigned)f2bf(a2[rr * 4 + 1]) << 16);
      p2k.y = (unsigned)f2bf(a2[rr * 4 + 2]) | ((unsigned)f2bf(a2[rr * 4 + 3]) << 16);
      *reinterpret_cast<uint2*>(G + (size_t)n * 128 + colbase) = p1k;
      *reinterpret_cast<uint2*>(P2 + (size_t)n * 64 + colbase) = p2k;
    }
  }
}

// c = relu(bn(in)); col stats of c; bf16 mirror into packed G (offset 64).
__global__ __launch_bounds__(256) void bnrelu_kernel(
    const float* __restrict__ in, const float* __restrict__ stats_in,
    const float* __restrict__ g_in, const float* __restrict__ b_in,
    float* __restrict__ out, float* __restrict__ stats_out,
    ushort* __restrict__ out_g, int N) {
  __shared__ float red[2][4][64];
  int tid = threadIdx.x;
  int lane = tid & 63, w = tid >> 6;
  float invN = 1.0f / (float)N;
  float m = stats_in[lane] * invN;
  float var = stats_in[64 + lane] * invN - m * m;
  float sc = g_in[lane] * rsqrtf(var + BN_EPS);
  float sh = b_in[lane] - m * sc;
  float ps = 0.f, pq = 0.f;
  int rows_per_grid = gridDim.x * (blockDim.x >> 6);
  for (int n = blockIdx.x * (blockDim.x >> 6) + w; n < N; n += rows_per_grid) {
    float x = fmaxf(in[(size_t)n * 64 + lane] * sc + sh, 0.f);
    out[(size_t)n * 64 + lane] = x;
    out_g[(size_t)n * 128 + lane] = f2bf(x);
    ps += x;
    pq += x * x;
  }
  if (stats_out) {
    red[0][w][lane] = ps;
    red[1][w][lane] = pq;
    __syncthreads();
    if (w == 0) {
      float s = red[0][0][lane] + red[0][1][lane] + red[0][2][lane] + red[0][3][lane];
      float q = red[1][0][lane] + red[1][1][lane] + red[1][2][lane] + red[1][3][lane];
      atomicAdd(&stats_out[lane], s);
      atomicAdd(&stats_out[64 + lane], q);
    }
  }
}

// FUSED per-layer edge walk, de-diverged: wave per dst node v; 8 groups x 8
// lanes; each group owns one edge per iter.  ALL lanes: load both 16B halves
// of the 256B record G[s]=[P1row|cbrow], compute score (phase A), then agg
// (phase B).  Epilogue: zb[v] = T(c[v]) + wave-reduced agg.
template <int TR>
__global__ __launch_bounds__(256) void score_agg_kernel(
    const ushort* __restrict__ G, const ushort* __restrict__ P2,
    const float* __restrict__ c, const int* __restrict__ rowstart,
    const int2* __restrict__ epack, const float* __restrict__ W2,
    const float* __restrict__ b2, const float* __restrict__ stats_tr,
    const float* __restrict__ g_tr, const float* __restrict__ b_tr,
    float2* __restrict__ sc, float* __restrict__ zb, int N, int first) {
  int lane = threadIdx.x & 63;
  int v = blockIdx.x * 4 + (threadIdx.x >> 6);
  if (v >= N) return;
  int grp = lane >> 3;  // 0..7 : edge slot
  int sub = lane & 7;   // feature octet
  float w[16];
  {
    const float4* wp = reinterpret_cast<const float4*>(W2 + sub * 16);
#pragma unroll
    for (int k = 0; k < 4; ++k) {
      float4 t = wp[k];
      w[4 * k + 0] = t.x; w[4 * k + 1] = t.y; w[4 * k + 2] = t.z; w[4 * k + 3] = t.w;
    }
  }
  float bb0 = b2[0], bb1 = b2[1];
  uint4 pb = *reinterpret_cast<const uint4*>(P2 + (size_t)v * 64 + sub * 8);
  unsigned bv[4] = {pb.x, pb.y, pb.z, pb.w};
  float scv[8], shv[8];
  if (TR) {
    float invN = 1.0f / (float)N;
#pragma unroll
    for (int k = 0; k < 8; ++k) {
      int f = sub * 8 + k;
      float m = stats_tr[f] * invN;
      float var = stats_tr[64 + f] * invN - m * m;
      scv[k] = g_tr[f] * rsqrtf(var + BN_EPS);
      shv[k] = b_tr[f] - m * scv[k];
    }
  }
  float acc[8];
#pragma unroll
  for (int k = 0; k < 8; ++k) acc[k] = 0.f;

  int p0 = rowstart[v], p1 = rowstart[v + 1];
  for (int p = p0; p < p1; p += 8) {
    int pe = p + grp;
    bool act = pe < p1;
    float q0 = 0.f, q1 = 0.f;
    if (act) {
      int s = epack[pe].x;
      const ushort* rec = G + (size_t)s * 128 + sub * 8;
      uint4 ra = *reinterpret_cast<const uint4*>(rec);       // P1 half
      uint4 rb = *reinterpret_cast<const uint4*>(rec + 64);  // cb half
      unsigned av[4] = {ra.x, ra.y, ra.z, ra.w};
      unsigned xv[4] = {rb.x, rb.y, rb.z, rb.w};
      // phase A: score partial (all 8 lanes of the group)
#pragma unroll
      for (int k = 0; k < 4; ++k) {
        float v0 = fmaxf(bf2f_lo(av[k]) + bf2f_lo(bv[k]), 0.f);
        float v1 = fmaxf(bf2f_hi(av[k]) + bf2f_hi(bv[k]), 0.f);
        q0 = fmaf(v0, w[4 * k + 0], fmaf(v1, w[4 * k + 2], q0));
        q1 = fmaf(v0, w[4 * k + 1], fmaf(v1, w[4 * k + 3], q1));
      }
      // phase B: agg accumulate (all 8 lanes; lane covers its feature octet)
#pragma unroll
      for (int k = 0; k < 4; ++k) {
        float x0 = bf2f_lo(xv[k]);
        float x1 = bf2f_hi(xv[k]);
        if (TR) {
          x0 = fmaxf(x0 * scv[2 * k] + shv[2 * k], 0.f);
          x1 = fmaxf(x1 * scv[2 * k + 1] + shv[2 * k + 1], 0.f);
        }
        acc[2 * k] += x0;
        acc[2 * k + 1] += x1;
      }
    }
    // in-group score reduce (masks 1,2,4 stay within the 8-lane group)
#pragma unroll
    for (int mm = 1; mm < 8; mm <<= 1) {
      q0 += __shfl_xor(q0, mm);
      q1 += __shfl_xor(q1, mm);
    }
    if (act && sub == 0) {
      float o0 = q0 + bb0, o1 = q1 + bb1;
      if (!first) {
        float2 prev = sc[pe];
        o0 += prev.x;
        o1 += prev.y;
      }
      sc[pe] = make_float2(o0, o1);
    }
  }
  // cross-group agg reduce (lanes with same sub across 8 groups)
#pragma unroll
  for (int k = 0; k < 8; ++k) {
    acc[k] += __shfl_xor(acc[k], 8);
    acc[k] += __shfl_xor(acc[k], 16);
    acc[k] += __shfl_xor(acc[k], 32);
  }
  if (grp == 0) {
    const float* cv = c + (size_t)v * 64 + sub * 8;
    float4 c0 = *reinterpret_cast<const float4*>(cv);
    float4 c1 = *reinterpret_cast<const float4*>(cv + 4);
    float cf[8] = {c0.x, c0.y, c0.z, c0.w, c1.x, c1.y, c1.z, c1.w};
    float ov[8];
#pragma unroll
    for (int k = 0; k < 8; ++k) {
      float x = cf[k];
      if (TR) x = fmaxf(x * scv[k] + shv[k], 0.f);
      ov[k] = acc[k] + x;
    }
    float* zp = zb + (size_t)v * 64 + sub * 8;
    *reinterpret_cast<float4*>(zp) = make_float4(ov[0], ov[1], ov[2], ov[3]);
    *reinterpret_cast<float4*>(zp + 4) = make_float4(ov[4], ov[5], ov[6], ov[7]);
  }
}

// score-only CSR walk for the LAST rep: adds prev accumulation from sc[] and
// writes final score directly to out[orig edge id] (no separate scatter).
__global__ __launch_bounds__(256) void edge_score_final_kernel(
    const ushort* __restrict__ G, const ushort* __restrict__ P2,
    const int* __restrict__ rowstart, const int2* __restrict__ epack,
    const float* __restrict__ W2, const float* __restrict__ b2,
    const float2* __restrict__ sc, float2* __restrict__ out, int N) {
  int lane = threadIdx.x & 63;
  int v = blockIdx.x * 4 + (threadIdx.x >> 6);
  if (v >= N) return;
  int sub = lane & 7;
  int grp = lane >> 3;
  float w[16];
  const float4* wp = reinterpret_cast<const float4*>(W2 + sub * 16);
#pragma unroll
  for (int k = 0; k < 4; ++k) {
    float4 t = wp[k];
    w[4 * k + 0] = t.x; w[4 * k + 1] = t.y; w[4 * k + 2] = t.z; w[4 * k + 3] = t.w;
  }
  float bb0 = b2[0], bb1 = b2[1];
  uint4 pb = *reinterpret_cast<const uint4*>(P2 + (size_t)v * 64 + sub * 8);
  unsigned bv[4] = {pb.x, pb.y, pb.z, pb.w};
  int p0 = rowstart[v], p1 = rowstart[v + 1];
  for (int p = p0 + grp; p < p1; p += 8) {
    int2 ep = epack[p];
    int s = ep.x;
    uint4 pa = *reinterpret_cast<const uint4*>(G + (size_t)s * 128 + sub * 8);
    unsigned av[4] = {pa.x, pa.y, pa.z, pa.w};
    float q0 = 0.f, q1 = 0.f;
#pragma unroll
    for (int k = 0; k < 4; ++k) {
      float v0 = fmaxf(bf2f_lo(av[k]) + bf2f_lo(bv[k]), 0.f);
      float v1 = fmaxf(bf2f_hi(av[k]) + bf2f_hi(bv[k]), 0.f);
      q0 = fmaf(v0, w[4 * k + 0], fmaf(v1, w[4 * k + 2], q0));
      q1 = fmaf(v0, w[4 * k + 1], fmaf(v1, w[4 * k + 3], q1));
    }
#pragma unroll
    for (int mm = 1; mm < 8; mm <<= 1) {
      q0 += __shfl_xor(q0, mm);
      q1 += __shfl_xor(q1, mm);
    }
    if (sub == 0) {
      float2 prev = sc[p];
      out[ep.y] = make_float2(q0 + bb0 + prev.x, q1 + bb1 + prev.y);
    }
  }
}

extern "C" void kernel_launch(void* const* d_in, const int* in_sizes, int n_in,
                              void* d_out, int out_size, void* d_ws, size_t ws_size,
                              hipStream_t stream) {
  const float* h          = (const float*)d_in[0];
  const int*   src        = (const int*)d_in[1];
  const int*   dst        = (const int*)d_in[2];
  const float* emb_W      = (const float*)d_in[3];
  const float* emb_b      = (const float*)d_in[4];
  const float* mlp_W1     = (const float*)d_in[5];
  const float* mlp_b1     = (const float*)d_in[6];
  const float* mlp_bn_g   = (const float*)d_in[7];
  const float* mlp_bn_b   = (const float*)d_in[8];
  const float* mlp_W2     = (const float*)d_in[9];
  const float* mlp_b2     = (const float*)d_in[10];
  const float* apply_bn_g = (const float*)d_in[11];
  const float* apply_bn_b = (const float*)d_in[12];
  const float* out_bn_g   = (const float*)d_in[13];
  const float* out_bn_b   = (const float*)d_in[14];
  const float* pred_W1    = (const float*)d_in[15];
  const float* pred_b1    = (const float*)d_in[16];
  const float* pred_W2    = (const float*)d_in[17];
  const float* pred_b2    = (const float*)d_in[18];

  const int N = in_sizes[0] / 64;
  const int E = in_sizes[1];
  const size_t NF = (size_t)N * 64;
  const int NB1 = (N + 1023) / 1024;  // scan3 requires NB1 <= 64 (N <= 65536)

  float* ws = (float*)d_ws;
  float* c   = ws;            // current node features (f32), pre-bn_out
  float* z1  = c + NF;
  float* zb  = z1 + NF;       // agg output; ALSO reused as z2 (disjoint lifetime)
  ushort* G  = (ushort*)(zb + NF);  // packed [N][128]: [0..63]=P1, [64..127]=cb
  ushort* P2 = G + (size_t)N * 128;
  int2*   epack = (int2*)(P2 + NF); // (src, orig edge id) per CSR slot
  float2* scbuf = (float2*)(epack + E);
  int* rowstart = (int*)(scbuf + E);          // N+1 (padded)
  int* cursor   = rowstart + (N + 64);
  int* partials = cursor + (N + 64);          // 64
  int* deg      = partials + 64;
  float* stats  = (float*)(deg + (N + 64));   // 9 slots x [sum(64), sumsq(64)]

  size_t need = (size_t)((char*)(stats + 9 * 128) - (char*)d_ws);
  if (need > ws_size) return;

  hipMemsetAsync(deg, 0, ((size_t)(N + 64) + 9 * 128) * sizeof(int), stream);

  const int gemmBlocks = (N + 63) / 64;
  const int nodeBlocks = (N + 3) / 4;

  // embedding: c = h @ emb_W + emb_b  (+ cb into packed G)
  gemm64_kernel<<<gemmBlocks, 256, 0, stream>>>(h, emb_W, emb_b, nullptr, nullptr,
                                                nullptr, c, nullptr, G + 64, N);
  // CSR build (by dst)
  hist_kernel<<<1024, 256, 0, stream>>>(dst, deg, E);
  scan1_kernel<<<NB1, 256, 0, stream>>>(deg, rowstart, partials, N);
  scan3_kernel<<<NB1, 256, 0, stream>>>(partials, rowstart, cursor, N, NB1, E);
  fill_kernel<<<1024, 256, 0, stream>>>(src, dst, cursor, epack, E);

  // rep 0: proj (identity) then fused score0 + agg(layer0)
  proj_kernel<<<gemmBlocks, 256, 0, stream>>>(c, pred_W1, pred_b1, nullptr, nullptr,
                                              nullptr, G, P2, N);
  score_agg_kernel<0><<<nodeBlocks, 256, 0, stream>>>(
      G, P2, c, rowstart, epack, pred_W2, pred_b2, nullptr, nullptr, nullptr,
      scbuf, zb, N, 1);

  for (int i = 0; i < 3; ++i) {
    float* st1 = stats + (size_t)(3 * i + 0) * 128;
    float* st2 = stats + (size_t)(3 * i + 1) * 128;
    float* st3 = stats + (size_t)(3 * i + 2) * 128;

    // z1 = zb @ W1 + b1  (+ stats st1)
    gemm64_kernel<<<gemmBlocks, 256, 0, stream>>>(zb, mlp_W1 + (size_t)i * 4096,
                                                  mlp_b1 + i * 64, nullptr, nullptr,
                                                  nullptr, z1, st1, nullptr, N);
    // z2(=zb) = relu(bn_mlp(z1)) @ W2 + b2  (+ stats st2)
    gemm64_kernel<<<gemmBlocks, 256, 0, stream>>>(z1, mlp_W2 + (size_t)i * 4096,
                                                  mlp_b2 + i * 64, st1,
                                                  mlp_bn_g + i * 64, mlp_bn_b + i * 64,
                                                  zb, st2, nullptr, N);
    // c = relu(bn_apply(z2))  (+ stats st3, cb into packed G); bn_out deferred
    bnrelu_kernel<<<784, 256, 0, stream>>>(zb, st2, apply_bn_g + i * 64,
                                           apply_bn_b + i * 64, c, st3, G + 64, N);
    // proj rep i+1 (applies deferred bn_out[i] via st3)
    proj_kernel<<<gemmBlocks, 256, 0, stream>>>(c, pred_W1 + (size_t)(i + 1) * 8192,
                                                pred_b1 + (i + 1) * 64, st3,
                                                out_bn_g + i * 64, out_bn_b + i * 64,
                                                G, P2, N);
    if (i < 2) {
      // fused: score rep i+1 + agg for layer i+1 (affine T via st3/out_bn)
      score_agg_kernel<1><<<nodeBlocks, 256, 0, stream>>>(
          G, P2, c, rowstart, epack, pred_W2 + (i + 1) * 128,
          pred_b2 + (i + 1) * 2, st3, out_bn_g + i * 64, out_bn_b + i * 64,
          scbuf, zb, N, 0);
    } else {
      // last rep: score only, write final result straight to d_out[eord]
      edge_score_final_kernel<<<nodeBlocks, 256, 0, stream>>>(
          G, P2, rowstart, epack, pred_W2 + (i + 1) * 128,
          pred_b2 + (i + 1) * 2, scbuf, (float2*)d_out, N);
    }
  }
}